// Round 3
// baseline (1473.428 us; speedup 1.0000x reference)
//
#include <hip/hip_runtime.h>

#define M_DIM 4096
#define N_DIM 8192
#define K_DIM 2048
#define NGRP 16
#define GSZ 512
#define EPSV 1e-5f

#define NX (M_DIM * K_DIM)            // x elems  = 8388608
#define NW (N_DIM * K_DIM)            // W elems  = 16777216
#define NY ((size_t)M_DIM * N_DIM)    // y elems  = 33554432

typedef __attribute__((ext_vector_type(8))) short bf16x8;
typedef __attribute__((ext_vector_type(4))) float f32x4;
typedef __attribute__((ext_vector_type(8))) short shortx8;

__device__ __forceinline__ float b2f(short u) {
    union { unsigned u32; float f; } c;
    c.u32 = ((unsigned)(unsigned short)u) << 16;
    return c.f;
}

__device__ __forceinline__ short f2b(float f) {
    union { float f; unsigned u; } c; c.f = f;
    unsigned r = (c.u + 0x7fffu + ((c.u >> 16) & 1u)) >> 16;
    return (short)r;
}

// ---------------- fp32 -> bf16 bulk convert (x then W, contiguous dst) -------
__global__ __launch_bounds__(256) void convert_kernel(
    const float* __restrict__ x, const float* __restrict__ W,
    short* __restrict__ dst)
{
    const size_t base = ((size_t)blockIdx.x * 256 + threadIdx.x) * 32;
    const float* src = (base < NX) ? (x + base) : (W + (base - NX));
    f32x4 v[8];
#pragma unroll
    for (int c = 0; c < 8; ++c) v[c] = *(const f32x4*)(src + c * 4);
#pragma unroll
    for (int c = 0; c < 4; ++c) {
        shortx8 o;
#pragma unroll
        for (int j = 0; j < 4; ++j) {
            o[j]     = f2b(v[2 * c][j]);
            o[j + 4] = f2b(v[2 * c + 1][j]);
        }
        *(shortx8*)(dst + base + c * 8) = o;
    }
}

// ------------- 256x256 bf16 GEMM, ring-2 LDS (64 KiB) -> 2 blocks/CU ---------
// C = A @ W^T, bf16 in/out. BM=BN=256, BK=32, 512 thr = 8 waves (2Mx4N),
// per-wave output 128x64 (acc[8][4] f32x4, AGPR).
// Occupancy-first schedule (round-2 post-mortem: 1 block/CU made MFMA and
// LDS-read phases serialize, time/step = sum of pipes). Ring-2 = 64 KiB LDS
// -> 2 blocks/CU (16 waves, 4/SIMD): each block's lgkmcnt/barrier bubbles are
// hidden by the other block's MFMA waves; setprio now has cross-block wave
// diversity to arbitrate (T5 regime).
// Per step t: stage(t+1) -> vmcnt(4) [counted: t landed, t+1 stays in flight]
// -> B1 -> ds_read frags(t) -> lgkmcnt(0) -> B2 -> 32 MFMA.
// Hazards: stage(t+1) writes slot (t+1)&1, last read at step t-1, certified
// retired by step t-1's lgkmcnt(0)+B2 rendezvous. ldfrags(t) covered by
// vmcnt(4)+B1 (stage(t) issued one full step earlier). Tail drains vmcnt(0).
// LDS swizzle (verified zero-conflict): physical chunk p = c ^ ((row>>1)&3),
// pre-swizzled GLOBAL source (LDS dest of global_load_lds stays linear) +
// swizzled ds_read chunk.
#define BKS 32
#define NTILES (K_DIM / BKS)   // 64

__global__ __launch_bounds__(512, 4) void gemm256_bf16_kernel(
    const short* __restrict__ A, const short* __restrict__ W, short* __restrict__ C)
{
    __shared__ __align__(16) short lds[2 * 16384];   // 64 KiB: 2 x (A 16K + B 16K)

    const int tid  = threadIdx.x;
    const int lane = tid & 63;
    const int wave = tid >> 6;
    const int wr   = wave >> 2;        // 0..1  (M)
    const int wc   = wave & 3;         // 0..3  (N)

    // XCD-aware swizzle: 512 blocks, 512%8==0 -> bijective. XCD j gets a
    // contiguous swz range -> by in {2j,2j+1}: same-XCD blocks share A-panels
    // (1 MB each, L2-fit) instead of thrashing 8 panels into 4 MiB L2.
    const unsigned orig = blockIdx.x;
    const unsigned swz  = (orig & 7) * 64 + (orig >> 3);
    const int blockCol = (swz & 31) * 256;   // N: 32 tiles
    const int blockRow = (swz >> 5) * 256;   // M: 16 tiles

    // staging: linear chunk q (0..1023) -> LDS slot q*16B (row=q>>2, p=q&3);
    // fetch global chunk c = p ^ ((row>>1)&3) = (q&3) ^ ((q>>3)&3).
    const int q0 = tid, q1 = tid + 512;
    const int sr0 = q0 >> 2, sc0 = (q0 & 3) ^ ((q0 >> 3) & 3);
    const int sr1 = q1 >> 2, sc1 = (q1 & 3) ^ ((q1 >> 3) & 3);
    const int offA0 = (blockRow + sr0) * K_DIM + sc0 * 8;
    const int offA1 = (blockRow + sr1) * K_DIM + sc1 * 8;
    const int offB0 = (blockCol + sr0) * K_DIM + sc0 * 8;
    const int offB1 = (blockCol + sr1) * K_DIM + sc1 * 8;

    // fragment reads: row = warpBase + i*16 + fr (bases multiple of 16 ->
    // (row>>1)&3 == (fr>>1)&3), logical chunk c = lane>>4,
    // physical p = c ^ ((fr>>1)&3).
    const int fr    = lane & 15;
    const int pbyte = ((lane >> 4) ^ ((fr >> 1) & 3)) * 16;
    const int aBase = (wr * 128 + fr) * 64 + pbyte;   // byte offset, +i*1024
    const int bBase = (wc * 64  + fr) * 64 + pbyte;   // byte offset, +j*1024

    f32x4 acc[8][4] = {};

    auto stageT = [&](int t) {
        short* dA = lds + (t & 1) * 16384;
        short* dB = dA + 8192;
        const int ko = t * BKS;
        __builtin_amdgcn_global_load_lds(
            (const __attribute__((address_space(1))) void*)(A + offA0 + ko),
            (__attribute__((address_space(3))) void*)(dA + q0 * 8), 16, 0, 0);
        __builtin_amdgcn_global_load_lds(
            (const __attribute__((address_space(1))) void*)(W + offB0 + ko),
            (__attribute__((address_space(3))) void*)(dB + q0 * 8), 16, 0, 0);
        __builtin_amdgcn_global_load_lds(
            (const __attribute__((address_space(1))) void*)(A + offA1 + ko),
            (__attribute__((address_space(3))) void*)(dA + q1 * 8), 16, 0, 0);
        __builtin_amdgcn_global_load_lds(
            (const __attribute__((address_space(1))) void*)(W + offB1 + ko),
            (__attribute__((address_space(3))) void*)(dB + q1 * 8), 16, 0, 0);
    };

    // prologue: stage tile 0 only (4 loads in flight)
    stageT(0);

    for (int t = 0; t < NTILES; ++t) {
        // stage next tile into the other slot (WAR-safe: slot last read at
        // step t-1, certified by that step's lgkmcnt(0)+B2 rendezvous)
        if (t + 1 < NTILES) {
            stageT(t + 1);
            // outstanding: stage(t) 4 oldest + stage(t+1) 4 newest
            asm volatile("s_waitcnt vmcnt(4)" ::: "memory");   // tile t landed
        } else {
            asm volatile("s_waitcnt vmcnt(0)" ::: "memory");   // tail
        }
        __builtin_amdgcn_sched_barrier(0);
        __builtin_amdgcn_s_barrier();            // B1: tile t visible block-wide
        __builtin_amdgcn_sched_barrier(0);

        const char* bufA = (const char*)lds + (t & 1) * 32768;
        const char* bufB = bufA + 16384;
        bf16x8 af[8], bfv[4];
#pragma unroll
        for (int i = 0; i < 8; ++i)
            af[i] = *(const bf16x8*)(bufA + aBase + i * 1024);
#pragma unroll
        for (int j = 0; j < 4; ++j)
            bfv[j] = *(const bf16x8*)(bufB + bBase + j * 1024);
        asm volatile("s_waitcnt lgkmcnt(0)" ::: "memory");
        __builtin_amdgcn_sched_barrier(0);
        __builtin_amdgcn_s_barrier();            // B2: all waves' reads retired
        __builtin_amdgcn_sched_barrier(0);

        __builtin_amdgcn_s_setprio(1);
#pragma unroll
        for (int i = 0; i < 8; ++i)
#pragma unroll
            for (int j = 0; j < 4; ++j)
                acc[i][j] = __builtin_amdgcn_mfma_f32_16x16x32_bf16(
                    af[i], bfv[j], acc[i][j], 0, 0, 0);
        __builtin_amdgcn_s_setprio(0);
    }

    // C/D layout: col=lane&15, row=(lane>>4)*4+reg
    const int er = (lane >> 4) * 4;
    const int ec = lane & 15;
#pragma unroll
    for (int i = 0; i < 8; ++i) {
        const int rr = blockRow + wr * 128 + i * 16 + er;
#pragma unroll
        for (int j = 0; j < 4; ++j) {
            const int cc = blockCol + wc * 64 + j * 16 + ec;
#pragma unroll
            for (int r = 0; r < 4; ++r)
                C[(size_t)(rr + r) * N_DIM + cc] = f2b(acc[i][j][r]);
        }
    }
}

// ------------- GN epilogue: read bf16 y, +bias, groupnorm, silu*mw*silu, fp32 out
__global__ __launch_bounds__(256) void gn_silu_bf16_kernel(
    const short* __restrict__ Y,
    const float* __restrict__ bias,
    const float* __restrict__ gnw,
    const float* __restrict__ gnb,
    const float* __restrict__ mw,
    float* __restrict__ out)
{
    const int lane = threadIdx.x & 63;
    const int wave = threadIdx.x >> 6;
    const unsigned gid = blockIdx.x * 4u + wave;     // 65536 groups
    const unsigned row = gid >> 4;
    const unsigned grp = gid & 15;
    const int col = grp * GSZ + lane * 8;
    const size_t off = (size_t)row * N_DIM + col;

    bf16x8 v = *(const bf16x8*)(Y + off);
    f32x4 b0 = *(const f32x4*)(bias + col);
    f32x4 b1 = *(const f32x4*)(bias + col + 4);

    float y[8];
    float s = 0.f, s2 = 0.f;
#pragma unroll
    for (int j = 0; j < 8; ++j) {
        y[j] = b2f(v[j]) + (j < 4 ? b0[j] : b1[j - 4]);
        s  += y[j];
        s2 += y[j] * y[j];
    }
#pragma unroll
    for (int d = 1; d < 64; d <<= 1) {
        s  += __shfl_xor(s,  d, 64);
        s2 += __shfl_xor(s2, d, 64);
    }
    const float mean = s * (1.0f / GSZ);
    const float var  = s2 * (1.0f / GSZ) - mean * mean;
    const float inv  = rsqrtf(var + EPSV);

    f32x4 w0 = *(const f32x4*)(gnw + col);
    f32x4 w1 = *(const f32x4*)(gnw + col + 4);
    f32x4 g0 = *(const f32x4*)(gnb + col);
    f32x4 g1 = *(const f32x4*)(gnb + col + 4);
    f32x4 m0 = *(const f32x4*)(mw + col);
    f32x4 m1 = *(const f32x4*)(mw + col + 4);

    f32x4 o0, o1;
#pragma unroll
    for (int j = 0; j < 8; ++j) {
        float gwv = j < 4 ? w0[j] : w1[j - 4];
        float gbv = j < 4 ? g0[j] : g1[j - 4];
        float mwv = j < 4 ? m0[j] : m1[j - 4];
        float n  = (y[j] - mean) * inv * gwv + gbv;
        float s1 = n / (1.f + __expf(-n));
        float m  = s1 * mwv;
        float r  = m / (1.f + __expf(-m));
        if (j < 4) o0[j] = r; else o1[j - 4] = r;
    }
    *(f32x4*)(out + off)     = o0;
    *(f32x4*)(out + off + 4) = o1;
}

// ================== fallback path (round-2, known-good) ======================
__global__ __launch_bounds__(256) void gemm_bt_f32_kernel(
    const float* __restrict__ A, const float* __restrict__ W, float* __restrict__ C)
{
    __shared__ __align__(16) short ldsA[128 * 32];
    __shared__ __align__(16) short ldsB[128 * 32];

    const int tid  = threadIdx.x;
    const int lane = tid & 63;
    const int wave = tid >> 6;
    const int blockRow = blockIdx.y * 128;
    const int blockCol = blockIdx.x * 128;
    const int srow = tid >> 1;
    const int scol = (tid & 1) * 16;
    const int wm  = (wave >> 1) * 64;
    const int wn  = (wave & 1) * 64;
    const int fr  = lane & 15;
    const int fko = (lane >> 4) * 8;

    f32x4 acc[4][4] = {};
    const size_t aRowOff = (size_t)(blockRow + srow) * K_DIM;
    const size_t wRowOff = (size_t)(blockCol + srow) * K_DIM;

    for (int k0 = 0; k0 < K_DIM; k0 += 32) {
        f32x4 va0 = *(const f32x4*)(A + aRowOff + k0 + scol);
        f32x4 va1 = *(const f32x4*)(A + aRowOff + k0 + scol + 4);
        f32x4 va2 = *(const f32x4*)(A + aRowOff + k0 + scol + 8);
        f32x4 va3 = *(const f32x4*)(A + aRowOff + k0 + scol + 12);
        f32x4 vb0 = *(const f32x4*)(W + wRowOff + k0 + scol);
        f32x4 vb1 = *(const f32x4*)(W + wRowOff + k0 + scol + 4);
        f32x4 vb2 = *(const f32x4*)(W + wRowOff + k0 + scol + 8);
        f32x4 vb3 = *(const f32x4*)(W + wRowOff + k0 + scol + 12);
        bf16x8 a0, a1, b0, b1;
#pragma unroll
        for (int j = 0; j < 4; ++j) {
            a0[j] = f2b(va0[j]); a0[j + 4] = f2b(va1[j]);
            a1[j] = f2b(va2[j]); a1[j + 4] = f2b(va3[j]);
            b0[j] = f2b(vb0[j]); b0[j + 4] = f2b(vb1[j]);
            b1[j] = f2b(vb2[j]); b1[j + 4] = f2b(vb3[j]);
        }
        *(bf16x8*)(ldsA + srow * 32 + scol)     = a0;
        *(bf16x8*)(ldsA + srow * 32 + scol + 8) = a1;
        *(bf16x8*)(ldsB + srow * 32 + scol)     = b0;
        *(bf16x8*)(ldsB + srow * 32 + scol + 8) = b1;
        __syncthreads();

        bf16x8 af[4], bfv[4];
#pragma unroll
        for (int i = 0; i < 4; ++i) {
            af[i]  = *(const bf16x8*)(ldsA + (wm + i * 16 + fr) * 32 + fko);
            bfv[i] = *(const bf16x8*)(ldsB + (wn + i * 16 + fr) * 32 + fko);
        }
#pragma unroll
        for (int i = 0; i < 4; ++i)
#pragma unroll
            for (int j = 0; j < 4; ++j)
                acc[i][j] = __builtin_amdgcn_mfma_f32_16x16x32_bf16(
                    af[i], bfv[j], acc[i][j], 0, 0, 0);
        __syncthreads();
    }

    const int er = (lane >> 4) * 4;
    const int ec = lane & 15;
#pragma unroll
    for (int i = 0; i < 4; ++i) {
        const int r0 = blockRow + wm + i * 16 + er;
#pragma unroll
        for (int j = 0; j < 4; ++j) {
            const int c0 = blockCol + wn + j * 16 + ec;
#pragma unroll
            for (int r = 0; r < 4; ++r)
                C[(size_t)(r0 + r) * N_DIM + c0] = acc[i][j][r];
        }
    }
}

__global__ __launch_bounds__(256) void gn_silu_f32_kernel(
    float* __restrict__ Y,
    const float* __restrict__ bias,
    const float* __restrict__ gnw,
    const float* __restrict__ gnb,
    const float* __restrict__ mw)
{
    const int lane = threadIdx.x & 63;
    const int wave = threadIdx.x >> 6;
    const unsigned gid = blockIdx.x * 4u + wave;
    const unsigned row = gid >> 4;
    const unsigned grp = gid & 15;
    const int col = grp * GSZ + lane * 8;
    const size_t off = (size_t)row * N_DIM + col;

    f32x4 v0 = *(const f32x4*)(Y + off);
    f32x4 v1 = *(const f32x4*)(Y + off + 4);
    f32x4 b0 = *(const f32x4*)(bias + col);
    f32x4 b1 = *(const f32x4*)(bias + col + 4);

    float y[8];
    float s = 0.f, s2 = 0.f;
#pragma unroll
    for (int j = 0; j < 8; ++j) {
        y[j] = (j < 4 ? v0[j] + b0[j] : v1[j - 4] + b1[j - 4]);
        s += y[j]; s2 += y[j] * y[j];
    }
#pragma unroll
    for (int d = 1; d < 64; d <<= 1) {
        s  += __shfl_xor(s,  d, 64);
        s2 += __shfl_xor(s2, d, 64);
    }
    const float mean = s * (1.0f / GSZ);
    const float var  = s2 * (1.0f / GSZ) - mean * mean;
    const float inv  = rsqrtf(var + EPSV);

    f32x4 w0 = *(const f32x4*)(gnw + col);
    f32x4 w1 = *(const f32x4*)(gnw + col + 4);
    f32x4 g0 = *(const f32x4*)(gnb + col);
    f32x4 g1 = *(const f32x4*)(gnb + col + 4);
    f32x4 m0 = *(const f32x4*)(mw + col);
    f32x4 m1 = *(const f32x4*)(mw + col + 4);

    f32x4 o0, o1;
#pragma unroll
    for (int j = 0; j < 8; ++j) {
        float gwv = j < 4 ? w0[j] : w1[j - 4];
        float gbv = j < 4 ? g0[j] : g1[j - 4];
        float mwv = j < 4 ? m0[j] : m1[j - 4];
        float n  = (y[j] - mean) * inv * gwv + gbv;
        float s1 = n / (1.f + __expf(-n));
        float m  = s1 * mwv;
        float r  = m / (1.f + __expf(-m));
        if (j < 4) o0[j] = r; else o1[j - 4] = r;
    }
    *(f32x4*)(Y + off)     = o0;
    *(f32x4*)(Y + off + 4) = o1;
}

extern "C" void kernel_launch(void* const* d_in, const int* in_sizes, int n_in,
                              void* d_out, int out_size, void* d_ws, size_t ws_size,
                              hipStream_t stream)
{
    const float* x   = (const float*)d_in[0];
    const float* W   = (const float*)d_in[1];
    const float* b   = (const float*)d_in[2];
    const float* gnw = (const float*)d_in[3];
    const float* gnb = (const float*)d_in[4];
    const float* mw  = (const float*)d_in[5];
    float* out = (float*)d_out;

    // ws layout: xb[NX] | Wb[NW] | yb[NY]  (bf16 shorts) = 117,440,512 bytes
    const size_t need = ((size_t)NX + NW + NY) * sizeof(short);
    const int ngroups = M_DIM * NGRP;       // 65536

    if (ws_size >= need) {
        short* xb = (short*)d_ws;
        short* Wb = xb + NX;
        short* yb = Wb + NW;

        convert_kernel<<<(NX + NW) / (256 * 32), 256, 0, stream>>>(x, W, xb);
        gemm256_bf16_kernel<<<512, 512, 0, stream>>>(xb, Wb, yb);
        gn_silu_bf16_kernel<<<ngroups / 4, 256, 0, stream>>>(yb, b, gnw, gnb, mw, out);
    } else {
        dim3 ggrid(N_DIM / 128, M_DIM / 128);
        gemm_bt_f32_kernel<<<ggrid, 256, 0, stream>>>(x, W, out);
        gn_silu_f32_kernel<<<ngroups / 4, 256, 0, stream>>>(out, b, gnw, gnb, mw);
    }
}

// Round 4
// 370.228 us; speedup vs baseline: 3.9798x; 3.9798x over previous
//
#include <hip/hip_runtime.h>

#define M_DIM 4096
#define N_DIM 8192
#define K_DIM 2048
#define NGRP 16
#define GSZ 512
#define EPSV 1e-5f

#define NX (M_DIM * K_DIM)            // x elems  = 8388608
#define NW (N_DIM * K_DIM)            // W elems  = 16777216
#define NY ((size_t)M_DIM * N_DIM)    // y elems  = 33554432

typedef __attribute__((ext_vector_type(8))) short bf16x8;
typedef __attribute__((ext_vector_type(4))) float f32x4;
typedef __attribute__((ext_vector_type(8))) short shortx8;

__device__ __forceinline__ float b2f(short u) {
    union { unsigned u32; float f; } c;
    c.u32 = ((unsigned)(unsigned short)u) << 16;
    return c.f;
}

__device__ __forceinline__ short f2b(float f) {
    union { float f; unsigned u; } c; c.f = f;
    unsigned r = (c.u + 0x7fffu + ((c.u >> 16) & 1u)) >> 16;
    return (short)r;
}

// ---------------- fp32 -> bf16 bulk convert (x then W, contiguous dst) -------
__global__ __launch_bounds__(256) void convert_kernel(
    const float* __restrict__ x, const float* __restrict__ W,
    short* __restrict__ dst)
{
    const size_t base = ((size_t)blockIdx.x * 256 + threadIdx.x) * 32;
    const float* src = (base < NX) ? (x + base) : (W + (base - NX));
    f32x4 v[8];
#pragma unroll
    for (int c = 0; c < 8; ++c) v[c] = *(const f32x4*)(src + c * 4);
#pragma unroll
    for (int c = 0; c < 4; ++c) {
        shortx8 o;
#pragma unroll
        for (int j = 0; j < 4; ++j) {
            o[j]     = f2b(v[2 * c][j]);
            o[j + 4] = f2b(v[2 * c + 1][j]);
        }
        *(shortx8*)(dst + base + c * 8) = o;
    }
}

// ---------- 256x256 bf16 GEMM, 8-phase fine-interleave (m201 structure) ------
// C = A @ W^T, bf16 in/out. BM=BN=256, 512 thr = 8 waves (2Mx4N), per-wave
// output 128x64 (acc[8][4] f32x4). Ring-4 of BK=32 subtile slots = 128 KiB
// LDS, 1 block/CU, 2 waves/SIMD. __launch_bounds__(512,2) -- NEVER (512,4):
// round-3 post-mortem: 4 waves/EU caps regs at 128 = acc alone -> acc spills
// to scratch (6 GB HBM traffic, 9x slower).
// Iter = 2 subtiles (t0=2i, t1=2i+1) = 8 phases. Phase = {frag ds_reads +
// 1 staging global_load_lds + s_barrier + 8 MFMA (one acc quadrant) +
// s_barrier}. Fine interleave so LDS-read segments of some waves overlap
// MFMA segments of others (m196/m201: the coarse whole-K-step split was the
// 43%-MfmaUtil cap).
// vmcnt ledger (counted, never 0 in main loop -- T4): 4 loads/subtile, stage
// sub t0+2 over phases 0-3, sub t1+2 over phases 4-7. At phase 3: outstanding
// = t1(4 oldest) + t0+2(4 newest) -> vmcnt(4) certifies t1 one phase before
// its first ds_read; barrier makes it block-wide. Same at phase 7 for t0+2.
// Prologue stages subs 0,1; vmcnt(4) certifies 0. Tail peeled: vmcnt(0) at
// sub-62 phase 3 certifies 63; no waits after.
// WAR on re-staged slot (t0+2)&3: last read at iter i-1 phases 0-3, >=4
// barriers earlier -- safe by barrier skew bound.
// LDS swizzle (zero-conflict, verified round 2): physical 16B chunk
// p = c ^ ((row>>1)&3); pre-swizzled GLOBAL source (global_load_lds LDS dest
// must stay linear) + swizzled ds_read chunk.
#define BKS 32
#define NTILES (K_DIM / BKS)   // 64 subtiles

__global__ __launch_bounds__(512, 2) void gemm256_bf16_kernel(
    const short* __restrict__ A, const short* __restrict__ W, short* __restrict__ C)
{
    __shared__ __align__(16) short lds[4 * 16384];   // 128 KiB, ring-4 x 32KB

    const int tid  = threadIdx.x;
    const int lane = tid & 63;
    const int wave = tid >> 6;
    const int wr   = wave >> 2;        // 0..1  (M)
    const int wc   = wave & 3;         // 0..3  (N)

    // XCD-aware bijective swizzle (512 blocks, 512%8==0): XCD j gets 64
    // consecutive swz -> 2 row-bands; A-panels (2 MB) stay L2-resident.
    const unsigned orig = blockIdx.x;
    const unsigned swz  = (orig & 7) * 64 + (orig >> 3);
    const int blockCol = (swz & 31) * 256;   // N: 32 tiles
    const int blockRow = (swz >> 5) * 256;   // M: 16 tiles

    // staging: linear chunk q (0..1023) -> LDS slot q*16B (row=q>>2, p=q&3);
    // fetch global chunk c = p ^ ((row>>1)&3) = (q&3) ^ ((q>>3)&3).
    const int q0 = tid, q1 = tid + 512;
    const int sr0 = q0 >> 2, sc0 = (q0 & 3) ^ ((q0 >> 3) & 3);
    const int sr1 = q1 >> 2, sc1 = (q1 & 3) ^ ((q1 >> 3) & 3);
    const int offA0 = (blockRow + sr0) * K_DIM + sc0 * 8;
    const int offA1 = (blockRow + sr1) * K_DIM + sc1 * 8;
    const int offB0 = (blockCol + sr0) * K_DIM + sc0 * 8;
    const int offB1 = (blockCol + sr1) * K_DIM + sc1 * 8;

    // fragment reads: row = warpBase + i*16 + fr (bases multiple of 16 ->
    // (row>>1)&3 == (fr>>1)&3), logical chunk c = lane>>4,
    // physical p = c ^ ((fr>>1)&3).
    const int fr    = lane & 15;
    const int pbyte = ((lane >> 4) ^ ((fr >> 1) & 3)) * 16;
    const int aBase = (wr * 128 + fr) * 64 + pbyte;   // byte off, +i*1024
    const int bBase = (wc * 64  + fr) * 64 + pbyte;   // byte off, +j*1024

    f32x4 acc[8][4] = {};
    bf16x8 af[8], bf[4];

    auto gll = [&](const short* g, short* l) {
        __builtin_amdgcn_global_load_lds(
            (const __attribute__((address_space(1))) void*)g,
            (__attribute__((address_space(3))) void*)l, 16, 0, 0);
    };
    // one of the 4 staging loads for subtile t (k is a literal at call sites)
    auto stage1 = [&](int t, int k) {
        short* dA = lds + (t & 3) * 16384;
        short* dB = dA + 8192;
        const int ko = t * BKS;
        if (k == 0)      gll(A + offA0 + ko, dA + q0 * 8);
        else if (k == 1) gll(W + offB0 + ko, dB + q0 * 8);
        else if (k == 2) gll(A + offA1 + ko, dA + q1 * 8);
        else             gll(W + offB1 + ko, dB + q1 * 8);
    };
    auto bar = [&]() {
        __builtin_amdgcn_sched_barrier(0);
        __builtin_amdgcn_s_barrier();
        __builtin_amdgcn_sched_barrier(0);
    };
    // 8 MFMA = one 64x32 acc quadrant (ib..ib+3, jb..jb+1)
    auto mf = [&](int ib, int jb) {
        __builtin_amdgcn_s_setprio(1);
#pragma unroll
        for (int i = 0; i < 4; ++i)
#pragma unroll
            for (int j = 0; j < 2; ++j)
                acc[ib + i][jb + j] = __builtin_amdgcn_mfma_f32_16x16x32_bf16(
                    af[ib + i], bf[jb + j], acc[ib + i][jb + j], 0, 0, 0);
        __builtin_amdgcn_s_setprio(0);
    };

    // 4 phases for one subtile. tstage/dostage/vm are literals at call sites.
    // vm: 4 = vmcnt(4) at phase 3, 0 = vmcnt(0), -1 = none.
    auto subtile = [&](int t, int tstage, bool dostage, int vm) {
        const char* bA = (const char*)lds + (t & 3) * 32768;
        const char* bB = bA + 16384;
        // P0: af0-3, bf0-1; quadrant (0..3, 0..1)
        af[0] = *(const bf16x8*)(bA + aBase);
        af[1] = *(const bf16x8*)(bA + aBase + 1024);
        af[2] = *(const bf16x8*)(bA + aBase + 2048);
        af[3] = *(const bf16x8*)(bA + aBase + 3072);
        bf[0] = *(const bf16x8*)(bB + bBase);
        bf[1] = *(const bf16x8*)(bB + bBase + 1024);
        if (dostage) stage1(tstage, 0);
        bar(); mf(0, 0); bar();
        // P1: bf2-3; quadrant (0..3, 2..3)
        bf[2] = *(const bf16x8*)(bB + bBase + 2048);
        bf[3] = *(const bf16x8*)(bB + bBase + 3072);
        if (dostage) stage1(tstage, 1);
        bar(); mf(0, 2); bar();
        // P2: af4-7; quadrant (4..7, 0..1)
        af[4] = *(const bf16x8*)(bA + aBase + 4096);
        af[5] = *(const bf16x8*)(bA + aBase + 5120);
        af[6] = *(const bf16x8*)(bA + aBase + 6144);
        af[7] = *(const bf16x8*)(bA + aBase + 7168);
        if (dostage) stage1(tstage, 2);
        bar(); mf(4, 0); bar();
        // P3: no reads; quadrant (4..7, 2..3); counted vmcnt certifies the
        // NEXT subtile one phase before its first ds_read.
        if (dostage) stage1(tstage, 3);
        if (vm == 4)      asm volatile("s_waitcnt vmcnt(4)" ::: "memory");
        else if (vm == 0) asm volatile("s_waitcnt vmcnt(0)" ::: "memory");
        bar(); mf(4, 2); bar();
    };

    // prologue: stage subs 0,1 (8 loads); certify sub 0; rendezvous.
    stage1(0, 0); stage1(0, 1); stage1(0, 2); stage1(0, 3);
    stage1(1, 0); stage1(1, 1); stage1(1, 2); stage1(1, 3);
    asm volatile("s_waitcnt vmcnt(4)" ::: "memory");
    bar();

    for (int i = 0; i < 31; ++i) {            // subtiles 0..61, staging 2..63
        const int t0 = 2 * i;
        subtile(t0,     t0 + 2, true, 4);
        subtile(t0 + 1, t0 + 3, true, 4);
    }
    subtile(62, 0, false, 0);                 // vmcnt(0) certifies sub 63
    subtile(63, 0, false, -1);

    // C/D layout: col=lane&15, row=(lane>>4)*4+reg
    const int er = (lane >> 4) * 4;
    const int ec = lane & 15;
#pragma unroll
    for (int i = 0; i < 8; ++i) {
        const int rr = blockRow + wr * 128 + i * 16 + er;
#pragma unroll
        for (int j = 0; j < 4; ++j) {
            const int cc = blockCol + wc * 64 + j * 16 + ec;
#pragma unroll
            for (int r = 0; r < 4; ++r)
                C[(size_t)(rr + r) * N_DIM + cc] = f2b(acc[i][j][r]);
        }
    }
}

// ------------- GN epilogue: read bf16 y, +bias, groupnorm, silu*mw*silu, fp32 out
__global__ __launch_bounds__(256) void gn_silu_bf16_kernel(
    const short* __restrict__ Y,
    const float* __restrict__ bias,
    const float* __restrict__ gnw,
    const float* __restrict__ gnb,
    const float* __restrict__ mw,
    float* __restrict__ out)
{
    const int lane = threadIdx.x & 63;
    const int wave = threadIdx.x >> 6;
    const unsigned gid = blockIdx.x * 4u + wave;     // 65536 groups
    const unsigned row = gid >> 4;
    const unsigned grp = gid & 15;
    const int col = grp * GSZ + lane * 8;
    const size_t off = (size_t)row * N_DIM + col;

    bf16x8 v = *(const bf16x8*)(Y + off);
    f32x4 b0 = *(const f32x4*)(bias + col);
    f32x4 b1 = *(const f32x4*)(bias + col + 4);

    float y[8];
    float s = 0.f, s2 = 0.f;
#pragma unroll
    for (int j = 0; j < 8; ++j) {
        y[j] = b2f(v[j]) + (j < 4 ? b0[j] : b1[j - 4]);
        s  += y[j];
        s2 += y[j] * y[j];
    }
#pragma unroll
    for (int d = 1; d < 64; d <<= 1) {
        s  += __shfl_xor(s,  d, 64);
        s2 += __shfl_xor(s2, d, 64);
    }
    const float mean = s * (1.0f / GSZ);
    const float var  = s2 * (1.0f / GSZ) - mean * mean;
    const float inv  = rsqrtf(var + EPSV);

    f32x4 w0 = *(const f32x4*)(gnw + col);
    f32x4 w1 = *(const f32x4*)(gnw + col + 4);
    f32x4 g0 = *(const f32x4*)(gnb + col);
    f32x4 g1 = *(const f32x4*)(gnb + col + 4);
    f32x4 m0 = *(const f32x4*)(mw + col);
    f32x4 m1 = *(const f32x4*)(mw + col + 4);

    f32x4 o0, o1;
#pragma unroll
    for (int j = 0; j < 8; ++j) {
        float gwv = j < 4 ? w0[j] : w1[j - 4];
        float gbv = j < 4 ? g0[j] : g1[j - 4];
        float mwv = j < 4 ? m0[j] : m1[j - 4];
        float n  = (y[j] - mean) * inv * gwv + gbv;
        float s1 = n / (1.f + __expf(-n));
        float m  = s1 * mwv;
        float r  = m / (1.f + __expf(-m));
        if (j < 4) o0[j] = r; else o1[j - 4] = r;
    }
    *(f32x4*)(out + off)     = o0;
    *(f32x4*)(out + off + 4) = o1;
}

// ================== fallback path (round-2, known-good) ======================
__global__ __launch_bounds__(256) void gemm_bt_f32_kernel(
    const float* __restrict__ A, const float* __restrict__ W, float* __restrict__ C)
{
    __shared__ __align__(16) short ldsA[128 * 32];
    __shared__ __align__(16) short ldsB[128 * 32];

    const int tid  = threadIdx.x;
    const int lane = tid & 63;
    const int wave = tid >> 6;
    const int blockRow = blockIdx.y * 128;
    const int blockCol = blockIdx.x * 128;
    const int srow = tid >> 1;
    const int scol = (tid & 1) * 16;
    const int wm  = (wave >> 1) * 64;
    const int wn  = (wave & 1) * 64;
    const int fr  = lane & 15;
    const int fko = (lane >> 4) * 8;

    f32x4 acc[4][4] = {};
    const size_t aRowOff = (size_t)(blockRow + srow) * K_DIM;
    const size_t wRowOff = (size_t)(blockCol + srow) * K_DIM;

    for (int k0 = 0; k0 < K_DIM; k0 += 32) {
        f32x4 va0 = *(const f32x4*)(A + aRowOff + k0 + scol);
        f32x4 va1 = *(const f32x4*)(A + aRowOff + k0 + scol + 4);
        f32x4 va2 = *(const f32x4*)(A + aRowOff + k0 + scol + 8);
        f32x4 va3 = *(const f32x4*)(A + aRowOff + k0 + scol + 12);
        f32x4 vb0 = *(const f32x4*)(W + wRowOff + k0 + scol);
        f32x4 vb1 = *(const f32x4*)(W + wRowOff + k0 + scol + 4);
        f32x4 vb2 = *(const f32x4*)(W + wRowOff + k0 + scol + 8);
        f32x4 vb3 = *(const f32x4*)(W + wRowOff + k0 + scol + 12);
        bf16x8 a0, a1, b0, b1;
#pragma unroll
        for (int j = 0; j < 4; ++j) {
            a0[j] = f2b(va0[j]); a0[j + 4] = f2b(va1[j]);
            a1[j] = f2b(va2[j]); a1[j + 4] = f2b(va3[j]);
            b0[j] = f2b(vb0[j]); b0[j + 4] = f2b(vb1[j]);
            b1[j] = f2b(vb2[j]); b1[j + 4] = f2b(vb3[j]);
        }
        *(bf16x8*)(ldsA + srow * 32 + scol)     = a0;
        *(bf16x8*)(ldsA + srow * 32 + scol + 8) = a1;
        *(bf16x8*)(ldsB + srow * 32 + scol)     = b0;
        *(bf16x8*)(ldsB + srow * 32 + scol + 8) = b1;
        __syncthreads();

        bf16x8 af[4], bfv[4];
#pragma unroll
        for (int i = 0; i < 4; ++i) {
            af[i]  = *(const bf16x8*)(ldsA + (wm + i * 16 + fr) * 32 + fko);
            bfv[i] = *(const bf16x8*)(ldsB + (wn + i * 16 + fr) * 32 + fko);
        }
#pragma unroll
        for (int i = 0; i < 4; ++i)
#pragma unroll
            for (int j = 0; j < 4; ++j)
                acc[i][j] = __builtin_amdgcn_mfma_f32_16x16x32_bf16(
                    af[i], bfv[j], acc[i][j], 0, 0, 0);
        __syncthreads();
    }

    const int er = (lane >> 4) * 4;
    const int ec = lane & 15;
#pragma unroll
    for (int i = 0; i < 4; ++i) {
        const int r0 = blockRow + wm + i * 16 + er;
#pragma unroll
        for (int j = 0; j < 4; ++j) {
            const int c0 = blockCol + wn + j * 16 + ec;
#pragma unroll
            for (int r = 0; r < 4; ++r)
                C[(size_t)(r0 + r) * N_DIM + c0] = acc[i][j][r];
        }
    }
}

__global__ __launch_bounds__(256) void gn_silu_f32_kernel(
    float* __restrict__ Y,
    const float* __restrict__ bias,
    const float* __restrict__ gnw,
    const float* __restrict__ gnb,
    const float* __restrict__ mw)
{
    const int lane = threadIdx.x & 63;
    const int wave = threadIdx.x >> 6;
    const unsigned gid = blockIdx.x * 4u + wave;
    const unsigned row = gid >> 4;
    const unsigned grp = gid & 15;
    const int col = grp * GSZ + lane * 8;
    const size_t off = (size_t)row * N_DIM + col;

    f32x4 v0 = *(const f32x4*)(Y + off);
    f32x4 v1 = *(const f32x4*)(Y + off + 4);
    f32x4 b0 = *(const f32x4*)(bias + col);
    f32x4 b1 = *(const f32x4*)(bias + col + 4);

    float y[8];
    float s = 0.f, s2 = 0.f;
#pragma unroll
    for (int j = 0; j < 8; ++j) {
        y[j] = (j < 4 ? v0[j] + b0[j] : v1[j - 4] + b1[j - 4]);
        s += y[j]; s2 += y[j] * y[j];
    }
#pragma unroll
    for (int d = 1; d < 64; d <<= 1) {
        s  += __shfl_xor(s,  d, 64);
        s2 += __shfl_xor(s2, d, 64);
    }
    const float mean = s * (1.0f / GSZ);
    const float var  = s2 * (1.0f / GSZ) - mean * mean;
    const float inv  = rsqrtf(var + EPSV);

    f32x4 w0 = *(const f32x4*)(gnw + col);
    f32x4 w1 = *(const f32x4*)(gnw + col + 4);
    f32x4 g0 = *(const f32x4*)(gnb + col);
    f32x4 g1 = *(const f32x4*)(gnb + col + 4);
    f32x4 m0 = *(const f32x4*)(mw + col);
    f32x4 m1 = *(const f32x4*)(mw + col + 4);

    f32x4 o0, o1;
#pragma unroll
    for (int j = 0; j < 8; ++j) {
        float gwv = j < 4 ? w0[j] : w1[j - 4];
        float gbv = j < 4 ? g0[j] : g1[j - 4];
        float mwv = j < 4 ? m0[j] : m1[j - 4];
        float n  = (y[j] - mean) * inv * gwv + gbv;
        float s1 = n / (1.f + __expf(-n));
        float m  = s1 * mwv;
        float r  = m / (1.f + __expf(-m));
        if (j < 4) o0[j] = r; else o1[j - 4] = r;
    }
    *(f32x4*)(Y + off)     = o0;
    *(f32x4*)(Y + off + 4) = o1;
}

extern "C" void kernel_launch(void* const* d_in, const int* in_sizes, int n_in,
                              void* d_out, int out_size, void* d_ws, size_t ws_size,
                              hipStream_t stream)
{
    const float* x   = (const float*)d_in[0];
    const float* W   = (const float*)d_in[1];
    const float* b   = (const float*)d_in[2];
    const float* gnw = (const float*)d_in[3];
    const float* gnb = (const float*)d_in[4];
    const float* mw  = (const float*)d_in[5];
    float* out = (float*)d_out;

    // ws layout: xb[NX] | Wb[NW] | yb[NY]  (bf16 shorts) = 117,440,512 bytes
    const size_t need = ((size_t)NX + NW + NY) * sizeof(short);
    const int ngroups = M_DIM * NGRP;       // 65536

    if (ws_size >= need) {
        short* xb = (short*)d_ws;
        short* Wb = xb + NX;
        short* yb = Wb + NW;

        convert_kernel<<<(NX + NW) / (256 * 32), 256, 0, stream>>>(x, W, xb);
        gemm256_bf16_kernel<<<512, 512, 0, stream>>>(xb, Wb, yb);
        gn_silu_bf16_kernel<<<ngroups / 4, 256, 0, stream>>>(yb, b, gnw, gnb, mw, out);
    } else {
        dim3 ggrid(N_DIM / 128, M_DIM / 128);
        gemm_bt_f32_kernel<<<ggrid, 256, 0, stream>>>(x, W, out);
        gn_silu_f32_kernel<<<ngroups / 4, 256, 0, stream>>>(out, b, gnw, gnb, mw);
    }
}

// Round 5
// 365.137 us; speedup vs baseline: 4.0353x; 1.0139x over previous
//
#include <hip/hip_runtime.h>

#define M_DIM 4096
#define N_DIM 8192
#define K_DIM 2048
#define NGRP 16
#define GSZ 512
#define EPSV 1e-5f

#define NX (M_DIM * K_DIM)            // x elems  = 8388608
#define NW (N_DIM * K_DIM)            // W elems  = 16777216
#define NY ((size_t)M_DIM * N_DIM)    // y elems  = 33554432

typedef __attribute__((ext_vector_type(8))) short bf16x8;
typedef __attribute__((ext_vector_type(4))) float f32x4;
typedef __attribute__((ext_vector_type(8))) short shortx8;

__device__ __forceinline__ float b2f(short u) {
    union { unsigned u32; float f; } c;
    c.u32 = ((unsigned)(unsigned short)u) << 16;
    return c.f;
}

__device__ __forceinline__ short f2b(float f) {
    union { float f; unsigned u; } c; c.f = f;
    unsigned r = (c.u + 0x7fffu + ((c.u >> 16) & 1u)) >> 16;
    return (short)r;
}

// ---------------- fp32 -> bf16 bulk convert (x then W, contiguous dst) -------
__global__ __launch_bounds__(256) void convert_kernel(
    const float* __restrict__ x, const float* __restrict__ W,
    short* __restrict__ dst)
{
    const size_t base = ((size_t)blockIdx.x * 256 + threadIdx.x) * 32;
    const float* src = (base < NX) ? (x + base) : (W + (base - NX));
    f32x4 v[8];
#pragma unroll
    for (int c = 0; c < 8; ++c) v[c] = *(const f32x4*)(src + c * 4);
#pragma unroll
    for (int c = 0; c < 4; ++c) {
        shortx8 o;
#pragma unroll
        for (int j = 0; j < 4; ++j) {
            o[j]     = f2b(v[2 * c][j]);
            o[j + 4] = f2b(v[2 * c + 1][j]);
        }
        *(shortx8*)(dst + base + c * 8) = o;
    }
}

// ---------- 256x256 bf16 GEMM, 2-phase/subtile, 16-MFMA clusters -------------
// C = A @ W^T, bf16 in/out. BM=BN=256, 512 thr = 8 waves (2Mx4N), per-wave
// output 128x64 (acc[8][4] f32x4). Ring-4 of BK=32 subtile slots = 128 KiB
// LDS, 1 block/CU, 2 waves/SIMD. __launch_bounds__(512,2) -- NEVER (512,4):
// 4 waves/EU caps regs at 128 = acc alone -> scratch spill (round-3: 9x).
// Round-4 post-mortem: phases with 8 MFMA (310 SIMD-cy) vs up to 48 CU-reads
// (576 LDS-cy) are LDS-dominated -> barrier exposes LDS time every phase,
// pipes additive (measured 2528 cy/subtile = 1242 MFMA + 1152 LDS + ovh).
// Fix = m201 balance: 16-MFMA clusters (620 SIMD-cy) cover the LDS pipe's
// service via wave skew inside the phase.
//   Phase A: read af0-3,bf0-3 (8 ds_read_b128) + 2 gll -> bar -> 16 MFMA
//            (i0-3 x j0-3) -> bar
//   Phase B: read af4-7 (4 ds, reusing af regs) + 2 gll + counted vmcnt ->
//            bar -> 16 MFMA (i4-7 x j0-3) -> bar
// vmcnt ledger (counted, never 0 until tail): 4 gll/subtile; during subtile t
// stage t+2. Entering t: outstanding = stage(t+1) 4. After t's 4 glls: 8.
// vmcnt(4) at t's phase B -> stage(t+1) landed, one barrier before t+1's
// reads. Prologue: stage 0,1; vmcnt(4) certifies 0. Tail: subtile 62 does
// vmcnt(0) (certifies 63); 63 stages/waits nothing.
// WAR: stage(t+2) targets slot (t+2)&3, last read at subtile t-2; those reads
// completed before t-2's final barrier (MFMA issue implies lgkm satisfied),
// and the glls are issued after it -> safe block-wide.
// LDS swizzle (zero-conflict, verified): physical 16B chunk
// p = c ^ ((row>>1)&3); pre-swizzled GLOBAL source (global_load_lds LDS dest
// must stay linear) + swizzled ds_read chunk.
// Grid: plain 2D (32,16), NO XCD swizzle -- round-4's swizzle gave each XCD
// a 32 MB B working set (>> 4 MiB L2): FETCH 98 -> 270 MB. Default raster
// shares one A-panel chip-wide and measured 98 MB.
#define BKS 32
#define NTILES (K_DIM / BKS)   // 64 subtiles

__global__ __launch_bounds__(512, 2) void gemm256_bf16_kernel(
    const short* __restrict__ A, const short* __restrict__ W, short* __restrict__ C)
{
    __shared__ __align__(16) short lds[4 * 16384];   // 128 KiB, ring-4 x 32KB

    const int tid  = threadIdx.x;
    const int lane = tid & 63;
    const int wave = tid >> 6;
    const int wr   = wave >> 2;        // 0..1  (M)
    const int wc   = wave & 3;         // 0..3  (N)
    const int blockRow = blockIdx.y * 256;
    const int blockCol = blockIdx.x * 256;

    // staging: linear chunk q (0..1023) -> LDS slot q*16B (row=q>>2, p=q&3);
    // fetch global chunk c = p ^ ((row>>1)&3) = (q&3) ^ ((q>>3)&3).
    const int q0 = tid, q1 = tid + 512;
    const int sr0 = q0 >> 2, sc0 = (q0 & 3) ^ ((q0 >> 3) & 3);
    const int sr1 = q1 >> 2, sc1 = (q1 & 3) ^ ((q1 >> 3) & 3);
    const int offA0 = (blockRow + sr0) * K_DIM + sc0 * 8;
    const int offA1 = (blockRow + sr1) * K_DIM + sc1 * 8;
    const int offB0 = (blockCol + sr0) * K_DIM + sc0 * 8;
    const int offB1 = (blockCol + sr1) * K_DIM + sc1 * 8;

    // fragment reads: row = warpBase + i*16 + fr (bases multiple of 16 ->
    // (row>>1)&3 == (fr>>1)&3), logical chunk c = lane>>4,
    // physical p = c ^ ((fr>>1)&3).
    const int fr    = lane & 15;
    const int pbyte = ((lane >> 4) ^ ((fr >> 1) & 3)) * 16;
    const int aBase = (wr * 128 + fr) * 64 + pbyte;   // byte off, +i*1024
    const int bBase = (wc * 64  + fr) * 64 + pbyte;   // byte off, +j*1024

    f32x4 acc[8][4] = {};
    bf16x8 af[4], bf[4];

    auto gll = [&](const short* g, short* l) {
        __builtin_amdgcn_global_load_lds(
            (const __attribute__((address_space(1))) void*)g,
            (__attribute__((address_space(3))) void*)l, 16, 0, 0);
    };
    // one of the 4 staging loads for subtile t (k literal at call sites)
    auto stage1 = [&](int t, int k) {
        short* dA = lds + (t & 3) * 16384;
        short* dB = dA + 8192;
        const int ko = t * BKS;
        if (k == 0)      gll(A + offA0 + ko, dA + q0 * 8);
        else if (k == 1) gll(W + offB0 + ko, dB + q0 * 8);
        else if (k == 2) gll(A + offA1 + ko, dA + q1 * 8);
        else             gll(W + offB1 + ko, dB + q1 * 8);
    };
    auto bar = [&]() {
        __builtin_amdgcn_sched_barrier(0);
        __builtin_amdgcn_s_barrier();
        __builtin_amdgcn_sched_barrier(0);
    };

    // 2 phases for one subtile; tstage/dostage/vm literals at call sites.
    // vm: 4 = vmcnt(4) at phase B, 0 = vmcnt(0), -1 = none.
    auto subtile = [&](int t, int tstage, bool dostage, int vm) {
        const char* bA = (const char*)lds + (t & 3) * 32768;
        const char* bB = bA + 16384;
        // ---- Phase A: i0-3 x j0-3 ----
        af[0] = *(const bf16x8*)(bA + aBase);
        af[1] = *(const bf16x8*)(bA + aBase + 1024);
        af[2] = *(const bf16x8*)(bA + aBase + 2048);
        af[3] = *(const bf16x8*)(bA + aBase + 3072);
        bf[0] = *(const bf16x8*)(bB + bBase);
        bf[1] = *(const bf16x8*)(bB + bBase + 1024);
        bf[2] = *(const bf16x8*)(bB + bBase + 2048);
        bf[3] = *(const bf16x8*)(bB + bBase + 3072);
        if (dostage) { stage1(tstage, 0); stage1(tstage, 1); }
        bar();
        __builtin_amdgcn_s_setprio(1);
#pragma unroll
        for (int i = 0; i < 4; ++i)
#pragma unroll
            for (int j = 0; j < 4; ++j)
                acc[i][j] = __builtin_amdgcn_mfma_f32_16x16x32_bf16(
                    af[i], bf[j], acc[i][j], 0, 0, 0);
        __builtin_amdgcn_s_setprio(0);
        bar();
        // ---- Phase B: i4-7 x j0-3 (af regs reused) ----
        af[0] = *(const bf16x8*)(bA + aBase + 4096);
        af[1] = *(const bf16x8*)(bA + aBase + 5120);
        af[2] = *(const bf16x8*)(bA + aBase + 6144);
        af[3] = *(const bf16x8*)(bA + aBase + 7168);
        if (dostage) { stage1(tstage, 2); stage1(tstage, 3); }
        if (vm == 4)      asm volatile("s_waitcnt vmcnt(4)" ::: "memory");
        else if (vm == 0) asm volatile("s_waitcnt vmcnt(0)" ::: "memory");
        bar();
        __builtin_amdgcn_s_setprio(1);
#pragma unroll
        for (int i = 0; i < 4; ++i)
#pragma unroll
            for (int j = 0; j < 4; ++j)
                acc[4 + i][j] = __builtin_amdgcn_mfma_f32_16x16x32_bf16(
                    af[i], bf[j], acc[4 + i][j], 0, 0, 0);
        __builtin_amdgcn_s_setprio(0);
        bar();
    };

    // prologue: stage subs 0,1 (8 loads); certify sub 0; rendezvous.
    stage1(0, 0); stage1(0, 1); stage1(0, 2); stage1(0, 3);
    stage1(1, 0); stage1(1, 1); stage1(1, 2); stage1(1, 3);
    asm volatile("s_waitcnt vmcnt(4)" ::: "memory");
    bar();

    for (int t = 0; t < NTILES - 2; ++t)      // subtiles 0..61, staging 2..63
        subtile(t, t + 2, true, 4);
    subtile(62, 0, false, 0);                 // vmcnt(0) certifies sub 63
    subtile(63, 0, false, -1);

    // C/D layout: col=lane&15, row=(lane>>4)*4+reg
    const int er = (lane >> 4) * 4;
    const int ec = lane & 15;
#pragma unroll
    for (int i = 0; i < 8; ++i) {
        const int rr = blockRow + wr * 128 + i * 16 + er;
#pragma unroll
        for (int j = 0; j < 4; ++j) {
            const int cc = blockCol + wc * 64 + j * 16 + ec;
#pragma unroll
            for (int r = 0; r < 4; ++r)
                C[(size_t)(rr + r) * N_DIM + cc] = f2b(acc[i][j][r]);
        }
    }
}

// ------------- GN epilogue: read bf16 y, +bias, groupnorm, silu*mw*silu, fp32 out
__global__ __launch_bounds__(256) void gn_silu_bf16_kernel(
    const short* __restrict__ Y,
    const float* __restrict__ bias,
    const float* __restrict__ gnw,
    const float* __restrict__ gnb,
    const float* __restrict__ mw,
    float* __restrict__ out)
{
    const int lane = threadIdx.x & 63;
    const int wave = threadIdx.x >> 6;
    const unsigned gid = blockIdx.x * 4u + wave;     // 65536 groups
    const unsigned row = gid >> 4;
    const unsigned grp = gid & 15;
    const int col = grp * GSZ + lane * 8;
    const size_t off = (size_t)row * N_DIM + col;

    bf16x8 v = *(const bf16x8*)(Y + off);
    f32x4 b0 = *(const f32x4*)(bias + col);
    f32x4 b1 = *(const f32x4*)(bias + col + 4);

    float y[8];
    float s = 0.f, s2 = 0.f;
#pragma unroll
    for (int j = 0; j < 8; ++j) {
        y[j] = b2f(v[j]) + (j < 4 ? b0[j] : b1[j - 4]);
        s  += y[j];
        s2 += y[j] * y[j];
    }
#pragma unroll
    for (int d = 1; d < 64; d <<= 1) {
        s  += __shfl_xor(s,  d, 64);
        s2 += __shfl_xor(s2, d, 64);
    }
    const float mean = s * (1.0f / GSZ);
    const float var  = s2 * (1.0f / GSZ) - mean * mean;
    const float inv  = rsqrtf(var + EPSV);

    f32x4 w0 = *(const f32x4*)(gnw + col);
    f32x4 w1 = *(const f32x4*)(gnw + col + 4);
    f32x4 g0 = *(const f32x4*)(gnb + col);
    f32x4 g1 = *(const f32x4*)(gnb + col + 4);
    f32x4 m0 = *(const f32x4*)(mw + col);
    f32x4 m1 = *(const f32x4*)(mw + col + 4);

    f32x4 o0, o1;
#pragma unroll
    for (int j = 0; j < 8; ++j) {
        float gwv = j < 4 ? w0[j] : w1[j - 4];
        float gbv = j < 4 ? g0[j] : g1[j - 4];
        float mwv = j < 4 ? m0[j] : m1[j - 4];
        float n  = (y[j] - mean) * inv * gwv + gbv;
        float s1 = n / (1.f + __expf(-n));
        float m  = s1 * mwv;
        float r  = m / (1.f + __expf(-m));
        if (j < 4) o0[j] = r; else o1[j - 4] = r;
    }
    *(f32x4*)(out + off)     = o0;
    *(f32x4*)(out + off + 4) = o1;
}

// ================== fallback path (round-2, known-good) ======================
__global__ __launch_bounds__(256) void gemm_bt_f32_kernel(
    const float* __restrict__ A, const float* __restrict__ W, float* __restrict__ C)
{
    __shared__ __align__(16) short ldsA[128 * 32];
    __shared__ __align__(16) short ldsB[128 * 32];

    const int tid  = threadIdx.x;
    const int lane = tid & 63;
    const int wave = tid >> 6;
    const int blockRow = blockIdx.y * 128;
    const int blockCol = blockIdx.x * 128;
    const int srow = tid >> 1;
    const int scol = (tid & 1) * 16;
    const int wm  = (wave >> 1) * 64;
    const int wn  = (wave & 1) * 64;
    const int fr  = lane & 15;
    const int fko = (lane >> 4) * 8;

    f32x4 acc[4][4] = {};
    const size_t aRowOff = (size_t)(blockRow + srow) * K_DIM;
    const size_t wRowOff = (size_t)(blockCol + srow) * K_DIM;

    for (int k0 = 0; k0 < K_DIM; k0 += 32) {
        f32x4 va0 = *(const f32x4*)(A + aRowOff + k0 + scol);
        f32x4 va1 = *(const f32x4*)(A + aRowOff + k0 + scol + 4);
        f32x4 va2 = *(const f32x4*)(A + aRowOff + k0 + scol + 8);
        f32x4 va3 = *(const f32x4*)(A + aRowOff + k0 + scol + 12);
        f32x4 vb0 = *(const f32x4*)(W + wRowOff + k0 + scol);
        f32x4 vb1 = *(const f32x4*)(W + wRowOff + k0 + scol + 4);
        f32x4 vb2 = *(const f32x4*)(W + wRowOff + k0 + scol + 8);
        f32x4 vb3 = *(const f32x4*)(W + wRowOff + k0 + scol + 12);
        bf16x8 a0, a1, b0, b1;
#pragma unroll
        for (int j = 0; j < 4; ++j) {
            a0[j] = f2b(va0[j]); a0[j + 4] = f2b(va1[j]);
            a1[j] = f2b(va2[j]); a1[j + 4] = f2b(va3[j]);
            b0[j] = f2b(vb0[j]); b0[j + 4] = f2b(vb1[j]);
            b1[j] = f2b(vb2[j]); b1[j + 4] = f2b(vb3[j]);
        }
        *(bf16x8*)(ldsA + srow * 32 + scol)     = a0;
        *(bf16x8*)(ldsA + srow * 32 + scol + 8) = a1;
        *(bf16x8*)(ldsB + srow * 32 + scol)     = b0;
        *(bf16x8*)(ldsB + srow * 32 + scol + 8) = b1;
        __syncthreads();

        bf16x8 af[4], bfv[4];
#pragma unroll
        for (int i = 0; i < 4; ++i) {
            af[i]  = *(const bf16x8*)(ldsA + (wm + i * 16 + fr) * 32 + fko);
            bfv[i] = *(const bf16x8*)(ldsB + (wn + i * 16 + fr) * 32 + fko);
        }
#pragma unroll
        for (int i = 0; i < 4; ++i)
#pragma unroll
            for (int j = 0; j < 4; ++j)
                acc[i][j] = __builtin_amdgcn_mfma_f32_16x16x32_bf16(
                    af[i], bfv[j], acc[i][j], 0, 0, 0);
        __syncthreads();
    }

    const int er = (lane >> 4) * 4;
    const int ec = lane & 15;
#pragma unroll
    for (int i = 0; i < 4; ++i) {
        const int r0 = blockRow + wm + i * 16 + er;
#pragma unroll
        for (int j = 0; j < 4; ++j) {
            const int c0 = blockCol + wn + j * 16 + ec;
#pragma unroll
            for (int r = 0; r < 4; ++r)
                C[(size_t)(r0 + r) * N_DIM + c0] = acc[i][j][r];
        }
    }
}

__global__ __launch_bounds__(256) void gn_silu_f32_kernel(
    float* __restrict__ Y,
    const float* __restrict__ bias,
    const float* __restrict__ gnw,
    const float* __restrict__ gnb,
    const float* __restrict__ mw)
{
    const int lane = threadIdx.x & 63;
    const int wave = threadIdx.x >> 6;
    const unsigned gid = blockIdx.x * 4u + wave;
    const unsigned row = gid >> 4;
    const unsigned grp = gid & 15;
    const int col = grp * GSZ + lane * 8;
    const size_t off = (size_t)row * N_DIM + col;

    f32x4 v0 = *(const f32x4*)(Y + off);
    f32x4 v1 = *(const f32x4*)(Y + off + 4);
    f32x4 b0 = *(const f32x4*)(bias + col);
    f32x4 b1 = *(const f32x4*)(bias + col + 4);

    float y[8];
    float s = 0.f, s2 = 0.f;
#pragma unroll
    for (int j = 0; j < 8; ++j) {
        y[j] = (j < 4 ? v0[j] + b0[j] : v1[j - 4] + b1[j - 4]);
        s += y[j]; s2 += y[j] * y[j];
    }
#pragma unroll
    for (int d = 1; d < 64; d <<= 1) {
        s  += __shfl_xor(s,  d, 64);
        s2 += __shfl_xor(s2, d, 64);
    }
    const float mean = s * (1.0f / GSZ);
    const float var  = s2 * (1.0f / GSZ) - mean * mean;
    const float inv  = rsqrtf(var + EPSV);

    f32x4 w0 = *(const f32x4*)(gnw + col);
    f32x4 w1 = *(const f32x4*)(gnw + col + 4);
    f32x4 g0 = *(const f32x4*)(gnb + col);
    f32x4 g1 = *(const f32x4*)(gnb + col + 4);
    f32x4 m0 = *(const f32x4*)(mw + col);
    f32x4 m1 = *(const f32x4*)(mw + col + 4);

    f32x4 o0, o1;
#pragma unroll
    for (int j = 0; j < 8; ++j) {
        float gwv = j < 4 ? w0[j] : w1[j - 4];
        float gbv = j < 4 ? g0[j] : g1[j - 4];
        float mwv = j < 4 ? m0[j] : m1[j - 4];
        float n  = (y[j] - mean) * inv * gwv + gbv;
        float s1 = n / (1.f + __expf(-n));
        float m  = s1 * mwv;
        float r  = m / (1.f + __expf(-m));
        if (j < 4) o0[j] = r; else o1[j - 4] = r;
    }
    *(f32x4*)(Y + off)     = o0;
    *(f32x4*)(Y + off + 4) = o1;
}

extern "C" void kernel_launch(void* const* d_in, const int* in_sizes, int n_in,
                              void* d_out, int out_size, void* d_ws, size_t ws_size,
                              hipStream_t stream)
{
    const float* x   = (const float*)d_in[0];
    const float* W   = (const float*)d_in[1];
    const float* b   = (const float*)d_in[2];
    const float* gnw = (const float*)d_in[3];
    const float* gnb = (const float*)d_in[4];
    const float* mw  = (const float*)d_in[5];
    float* out = (float*)d_out;

    // ws layout: xb[NX] | Wb[NW] | yb[NY]  (bf16 shorts) = 117,440,512 bytes
    const size_t need = ((size_t)NX + NW + NY) * sizeof(short);
    const int ngroups = M_DIM * NGRP;       // 65536

    if (ws_size >= need) {
        short* xb = (short*)d_ws;
        short* Wb = xb + NX;
        short* yb = Wb + NW;

        convert_kernel<<<(NX + NW) / (256 * 32), 256, 0, stream>>>(x, W, xb);
        dim3 g256(N_DIM / 256, M_DIM / 256);   // 32 x 16 = 512 blocks, plain raster
        gemm256_bf16_kernel<<<g256, 512, 0, stream>>>(xb, Wb, yb);
        gn_silu_bf16_kernel<<<ngroups / 4, 256, 0, stream>>>(yb, b, gnw, gnb, mw, out);
    } else {
        dim3 ggrid(N_DIM / 128, M_DIM / 128);
        gemm_bt_f32_kernel<<<ggrid, 256, 0, stream>>>(x, W, out);
        gn_silu_f32_kernel<<<ngroups / 4, 256, 0, stream>>>(out, b, gnw, gnb, mw);
    }
}